// Round 7
// baseline (2574.710 us; speedup 1.0000x reference)
//
#include <hip/hip_runtime.h>
#include <hip/hip_bf16.h>
#include <math.h>

// PaiNN forward, MI355X. Round 7: msg_kernel restructure —
//  (1) RBF values r[E,20] precomputed ONCE (layer/lane-invariant; kills 3x64x
//      redundant exps), msg inner loop = pure FMA;
//  (2) edge-parity split: 2 waves per node (2 nodes x 4 waves/block), LDS
//      partial combine -> half the serial chain, 2x resident waves;
//  (3) filt_w in bf16 (halves fw L2 traffic).
// GEMMs/elementwise unchanged from round 6. Static .bss scratch.

#define N_NODES 40000
#define N_EDGES 400000
#define NGAUSS  50
#define NLAY    3
#define NGRAPH  256

#define WS_BYTES (512ull * 1024 * 1024)
__device__ __align__(256) unsigned char g_ws[WS_BYTES];

typedef __attribute__((ext_vector_type(8))) short short8;
typedef __attribute__((ext_vector_type(4))) float f32x4;

__device__ __forceinline__ float relu_f(float x) { return fmaxf(x, 0.f); }
__device__ __forceinline__ unsigned short f2b(float x) {
  __hip_bfloat16 h = __float2bfloat16(x);
  return *reinterpret_cast<unsigned short*>(&h);
}
__device__ __forceinline__ float b2f_lo(unsigned int u) {
  return __uint_as_float(u << 16);
}
__device__ __forceinline__ float b2f_hi(unsigned int u) {
  return __uint_as_float(u & 0xffff0000u);
}

// ---------- f32 -> bf16 elementwise ----------
__global__ __launch_bounds__(256) void cvt_kernel(const float* __restrict__ in,
                                                  unsigned short* __restrict__ out,
                                                  int n) {
  int i = blockIdx.x * 256 + threadIdx.x;
  if (i < n) out[i] = f2b(in[i]);
}

// ---------- geometry ----------
__global__ __launch_bounds__(256) void geom_kernel(const int* __restrict__ src,
                                                   const int* __restrict__ dst,
                                                   const float* __restrict__ pos,
                                                   float4* __restrict__ geom) {
  int e = blockIdx.x * 256 + threadIdx.x;
  if (e >= N_EDGES) return;
  int s = src[e], d = dst[e];
  float dx = pos[s * 3 + 0] - pos[d * 3 + 0];
  float dy = pos[s * 3 + 1] - pos[d * 3 + 1];
  float dz = pos[s * 3 + 2] - pos[d * 3 + 2];
  float dist = sqrtf(dx * dx + dy * dy + dz * dz);
  float inv = 1.f / (dist + 1e-8f);
  geom[e] = make_float4(dx * inv, dy * inv, dz * inv, dist);
}

// ---------- per-edge truncated RBF table: r[e][i], i<17 (pad 20) ----------
__global__ __launch_bounds__(256) void rbf_kernel(const float4* __restrict__ geom,
                                                  float* __restrict__ rbf) {
  const float DELTA = 6.0f / 49.0f;
  const float INVD = 49.0f / 6.0f;
  const float CO = -0.5f * INVD * INVD;
  int idx = blockIdx.x * 256 + threadIdx.x;   // e*32 + i
  int e = idx >> 5, i = idx & 31;
  if (e >= N_EDGES || i >= 20) return;
  float d = geom[e].w;
  int glo = max(0, (int)ceilf(d * INVD - 8.f));
  int ghi = min(NGAUSS - 1, (int)floorf(d * INVD + 8.f));
  int g = glo + i;
  float r = 0.f;
  if (i < 17 && g <= ghi) {
    float diff = d - g * DELTA;
    r = __expf(CO * diff * diff);
  }
  rbf[(size_t)e * 20 + i] = r;
}

// ---------- CSR build ----------
__global__ __launch_bounds__(256) void hist_kernel(const int* __restrict__ dst,
                                                   int* __restrict__ deg) {
  int e = blockIdx.x * 256 + threadIdx.x;
  if (e < N_EDGES) atomicAdd(&deg[dst[e]], 1);
}

__global__ __launch_bounds__(1024) void scan_kernel(const int* __restrict__ deg,
                                                    int* __restrict__ off, int n) {
  __shared__ int wsum[16];
  __shared__ int ctot;
  int t = threadIdx.x, lane = t & 63, w = t >> 6;
  int carry = 0;
  for (int base = 0; base < n; base += 1024) {
    int i = base + t;
    int v = (i < n) ? deg[i] : 0;
    int x = v;
#pragma unroll
    for (int dd = 1; dd < 64; dd <<= 1) {
      int y = __shfl_up(x, dd);
      if (lane >= dd) x += y;
    }
    if (lane == 63) wsum[w] = x;
    __syncthreads();
    if (w == 0 && lane < 16) {
      int self = wsum[lane];
      int xs = self;
#pragma unroll
      for (int dd = 1; dd < 16; dd <<= 1) {
        int y = __shfl_up(xs, dd);
        if (lane >= dd) xs += y;
      }
      wsum[lane] = xs - self;
      if (lane == 15) ctot = xs;
    }
    __syncthreads();
    if (i < n) off[i] = carry + wsum[w] + (x - v);
    carry += ctot;
    __syncthreads();
  }
  if (t == 0) off[n] = carry;
}

__global__ __launch_bounds__(256) void fill_kernel(const int* __restrict__ dst,
                                                   const int* __restrict__ off,
                                                   int* __restrict__ cursor,
                                                   int* __restrict__ eid) {
  int e = blockIdx.x * 256 + threadIdx.x;
  if (e >= N_EDGES) return;
  int d = dst[e];
  int p = atomicAdd(&cursor[d], 1);
  eid[off[d] + p] = e;
}

// ---------- init: s = embed[z] (f32 + bf16), v = 0 (f32 + bf16) ----------
__global__ __launch_bounds__(256) void init_kernel(const int* __restrict__ z,
                                                   const float* __restrict__ embed,
                                                   float* __restrict__ s,
                                                   unsigned short* __restrict__ sb,
                                                   float* __restrict__ v,
                                                   unsigned short* __restrict__ vb) {
  int idx = blockIdx.x * 256 + threadIdx.x;
  if (idx < N_NODES * 384) { v[idx] = 0.f; vb[idx] = 0; }
  if (idx < N_NODES * 128) {
    int node = idx >> 7, c = idx & 127;
    float val = embed[z[node] * 128 + c];
    s[idx] = val;
    sb[idx] = f2b(val);
  }
}

// ---------- bf16 MFMA GEMM (tile 64x64, 4 waves, 16x16x32) ----------
#define KMAX 256
__global__ __launch_bounds__(256) void gemm_bf16(
    const unsigned short* __restrict__ A1, int lda1,
    const unsigned short* __restrict__ A2, int lda2, int kSplit,
    const unsigned short* __restrict__ B, int ldb,
    const float* __restrict__ bias,
    void* __restrict__ C, int ldc, int K, int doRelu, int outBf16) {
  __shared__ unsigned short Bt[64][KMAX + 8];
  int t = threadIdx.x;
  int lane = t & 63, w = t >> 6;
  int n0 = blockIdx.x * 64, m0 = blockIdx.y * 64;
  {
    int c4 = (t & 15) * 4;
    for (int k = t >> 4; k < K; k += 16) {
      uint2 v = *(const uint2*)&B[(size_t)k * ldb + n0 + c4];
      Bt[c4 + 0][k] = (unsigned short)(v.x & 0xffff);
      Bt[c4 + 1][k] = (unsigned short)(v.x >> 16);
      Bt[c4 + 2][k] = (unsigned short)(v.y & 0xffff);
      Bt[c4 + 3][k] = (unsigned short)(v.y >> 16);
    }
  }
  __syncthreads();

  int row = lane & 15;
  int kg = lane >> 4;
  int mrow = m0 + w * 16 + row;

  f32x4 acc[4];
#pragma unroll
  for (int i = 0; i < 4; ++i) acc[i] = (f32x4){0.f, 0.f, 0.f, 0.f};

  for (int ks = 0; ks < K; ks += 32) {
    int kk = ks + kg * 8;
    const unsigned short* Ap;
    int kloc;
    if (kk < kSplit) { Ap = A1 + (size_t)mrow * lda1; kloc = kk; }
    else             { Ap = A2 + (size_t)mrow * lda2; kloc = kk - kSplit; }
    short8 af = *(const short8*)&Ap[kloc];
#pragma unroll
    for (int nf = 0; nf < 4; ++nf) {
      short8 bf = *(const short8*)&Bt[nf * 16 + row][kk];
      acc[nf] = __builtin_amdgcn_mfma_f32_16x16x32_bf16(af, bf, acc[nf], 0, 0, 0);
    }
  }

#pragma unroll
  for (int nf = 0; nf < 4; ++nf) {
#pragma unroll
    for (int r = 0; r < 4; ++r) {
      int gr = m0 + w * 16 + kg * 4 + r;
      int gc = n0 + nf * 16 + row;
      float val = acc[nf][r] + (bias ? bias[gc] : 0.f);
      if (doRelu) val = relu_f(val);
      if (outBf16) ((unsigned short*)C)[(size_t)gr * ldc + gc] = f2b(val);
      else         ((float*)C)[(size_t)gr * ldc + gc] = val;
    }
  }
}

// ---------- per-edge filter weights from precomputed r + bf16 fw ----------
__device__ __forceinline__ void build_w(const float* __restrict__ rbf, int e,
                                        float d,
                                        const unsigned short* __restrict__ fwb,
                                        const float (&fbr)[3][2], int c2,
                                        float (&w)[3][2]) {
  const float INVD = 49.0f / 6.0f;
#pragma unroll
  for (int jj = 0; jj < 3; ++jj) { w[jj][0] = fbr[jj][0]; w[jj][1] = fbr[jj][1]; }
  int glo = max(0, (int)ceilf(d * INVD - 8.f));
  const float4* rp = (const float4*)(rbf + (size_t)e * 20);
  float4 ra = rp[0], rb = rp[1], rc = rp[2], rd = rp[3];
  float re_ = rbf[(size_t)e * 20 + 16];
  float rr[17] = {ra.x, ra.y, ra.z, ra.w, rb.x, rb.y, rb.z, rb.w,
                  rc.x, rc.y, rc.z, rc.w, rd.x, rd.y, rd.z, rd.w, re_};
#pragma unroll
  for (int i = 0; i < 17; ++i) {
    int g = min(glo + i, NGAUSS - 1);
    const unsigned short* fr = fwb + (size_t)g * 384 + c2;
#pragma unroll
    for (int jj = 0; jj < 3; ++jj) {
      unsigned int f = *(const unsigned int*)&fr[jj * 128];
      w[jj][0] = fmaf(rr[i], b2f_lo(f), w[jj][0]);
      w[jj][1] = fmaf(rr[i], b2f_hi(f), w[jj][1]);
    }
  }
}

__device__ __forceinline__ void accum_edge(const unsigned int (&sa)[3],
                                           const unsigned int (&vv)[3],
                                           const float (&w)[3][2],
                                           float gx, float gy, float gz,
                                           float (&ds)[2], float (&dv)[3][2]) {
  float gt[3][2];
#pragma unroll
  for (int jj = 0; jj < 3; ++jj) {
    gt[jj][0] = b2f_lo(sa[jj]) * w[jj][0];
    gt[jj][1] = b2f_hi(sa[jj]) * w[jj][1];
  }
  ds[0] += gt[0][0];
  ds[1] += gt[0][1];
  float dn[3] = {gx, gy, gz};
#pragma unroll
  for (int dd = 0; dd < 3; ++dd) {
    dv[dd][0] = fmaf(b2f_lo(vv[dd]), gt[1][0], fmaf(dn[dd], gt[2][0], dv[dd][0]));
    dv[dd][1] = fmaf(b2f_hi(vv[dd]), gt[1][1], fmaf(dn[dd], gt[2][1], dv[dd][1]));
  }
}

// ---------- fused edge message: 2 waves per node (edge parity split) ----------
// Block = 4 waves = 2 nodes. Wave (p, nl): node = blockIdx.x*2 + nl, edges
// e0+p, e0+p+2, ... Lane owns channels {2*lane, 2*lane+1}. LDS combine.
__global__ __launch_bounds__(256) void msg_kernel(const int* __restrict__ off,
                                                  const int* __restrict__ eid_arr,
                                                  const int* __restrict__ src_arr,
                                                  const float4* __restrict__ geom,
                                                  const float* __restrict__ rbf,
                                                  const unsigned short* __restrict__ s_all_b,
                                                  const unsigned short* __restrict__ fwb,
                                                  const float* __restrict__ fb,
                                                  const float* __restrict__ s_in,
                                                  const float* __restrict__ v_in,
                                                  const unsigned short* __restrict__ v_in_b,
                                                  float* __restrict__ s_out,
                                                  unsigned short* __restrict__ s_out_b,
                                                  float* __restrict__ v_out,
                                                  unsigned short* __restrict__ v_out_b) {
  __shared__ float cmb[2][512];
  int t = threadIdx.x;
  int lane = t & 63, w = t >> 6;
  int p = w & 1, nl = w >> 1;
  int node = blockIdx.x * 2 + nl;
  int c2 = lane * 2;
  float fbr[3][2];
#pragma unroll
  for (int jj = 0; jj < 3; ++jj) {
    float2 f = *(const float2*)&fb[jj * 128 + c2];
    fbr[jj][0] = f.x; fbr[jj][1] = f.y;
  }
  float ds[2] = {0.f, 0.f};
  float dv[3][2] = {{0.f}};
  int e0 = off[node], e1 = off[node + 1];
  int deg = e1 - e0;
  int cntp = (deg - p + 1) >> 1;   // this wave's edge count (parity p)
  if (cntp < 0) cntp = 0;

  for (int base = 0; base < cntp; base += 64) {
    int nc = min(64, cntp - base);
    int myS = 0, myE = 0;
    float4 myG = make_float4(0.f, 0.f, 0.f, 0.f);
    if (base + lane < cntp) {
      int q = e0 + p + 2 * (base + lane);
      myE = eid_arr[q];
      myS = src_arr[myE];
      myG = geom[myE];
    }
    int j = 0;
    for (; j + 1 < nc; j += 2) {
      int sA_ = __shfl(myS, j), sB_ = __shfl(myS, j + 1);
      int eA_ = __shfl(myE, j), eB_ = __shfl(myE, j + 1);
      float ax = __shfl(myG.x, j), ay = __shfl(myG.y, j);
      float az = __shfl(myG.z, j), ad = __shfl(myG.w, j);
      float bx = __shfl(myG.x, j + 1), by = __shfl(myG.y, j + 1);
      float bz = __shfl(myG.z, j + 1), bd = __shfl(myG.w, j + 1);
      const unsigned short* pas = s_all_b + (size_t)sA_ * 384 + c2;
      const unsigned short* pav = v_in_b + (size_t)sA_ * 384 + c2;
      const unsigned short* pbs = s_all_b + (size_t)sB_ * 384 + c2;
      const unsigned short* pbv = v_in_b + (size_t)sB_ * 384 + c2;
      unsigned int a_s[3] = {*(const unsigned int*)&pas[0],
                             *(const unsigned int*)&pas[128],
                             *(const unsigned int*)&pas[256]};
      unsigned int a_v[3] = {*(const unsigned int*)&pav[0],
                             *(const unsigned int*)&pav[128],
                             *(const unsigned int*)&pav[256]};
      unsigned int b_s[3] = {*(const unsigned int*)&pbs[0],
                             *(const unsigned int*)&pbs[128],
                             *(const unsigned int*)&pbs[256]};
      unsigned int b_v[3] = {*(const unsigned int*)&pbv[0],
                             *(const unsigned int*)&pbv[128],
                             *(const unsigned int*)&pbv[256]};
      float wA[3][2], wB[3][2];
      build_w(rbf, eA_, ad, fwb, fbr, c2, wA);
      build_w(rbf, eB_, bd, fwb, fbr, c2, wB);
      accum_edge(a_s, a_v, wA, ax, ay, az, ds, dv);
      accum_edge(b_s, b_v, wB, bx, by, bz, ds, dv);
    }
    if (j < nc) {
      int sA_ = __shfl(myS, j);
      int eA_ = __shfl(myE, j);
      float ax = __shfl(myG.x, j), ay = __shfl(myG.y, j);
      float az = __shfl(myG.z, j), ad = __shfl(myG.w, j);
      const unsigned short* pas = s_all_b + (size_t)sA_ * 384 + c2;
      const unsigned short* pav = v_in_b + (size_t)sA_ * 384 + c2;
      unsigned int a_s[3] = {*(const unsigned int*)&pas[0],
                             *(const unsigned int*)&pas[128],
                             *(const unsigned int*)&pas[256]};
      unsigned int a_v[3] = {*(const unsigned int*)&pav[0],
                             *(const unsigned int*)&pav[128],
                             *(const unsigned int*)&pav[256]};
      float wA[3][2];
      build_w(rbf, eA_, ad, fwb, fbr, c2, wA);
      accum_edge(a_s, a_v, wA, ax, ay, az, ds, dv);
    }
  }

  // combine parity partials via LDS: p0 writes, p1 adds + final store
  if (p == 0) {
    cmb[nl][c2] = ds[0];
    cmb[nl][c2 + 1] = ds[1];
#pragma unroll
    for (int dd = 0; dd < 3; ++dd) {
      cmb[nl][128 + dd * 128 + c2] = dv[dd][0];
      cmb[nl][128 + dd * 128 + c2 + 1] = dv[dd][1];
    }
  }
  __syncthreads();
  if (p == 1) {
    ds[0] += cmb[nl][c2];
    ds[1] += cmb[nl][c2 + 1];
#pragma unroll
    for (int dd = 0; dd < 3; ++dd) {
      dv[dd][0] += cmb[nl][128 + dd * 128 + c2];
      dv[dd][1] += cmb[nl][128 + dd * 128 + c2 + 1];
    }
    size_t sb = (size_t)node * 128 + c2;
    float2 si = *(const float2*)&s_in[sb];
    float2 so = make_float2(si.x + ds[0], si.y + ds[1]);
    *(float2*)&s_out[sb] = so;
    *(unsigned int*)&s_out_b[sb] =
        (unsigned int)f2b(so.x) | ((unsigned int)f2b(so.y) << 16);
#pragma unroll
    for (int dd = 0; dd < 3; ++dd) {
      size_t vb = (size_t)node * 384 + dd * 128 + c2;
      float2 vi = *(const float2*)&v_in[vb];
      float2 vo = make_float2(vi.x + dv[dd][0], vi.y + dv[dd][1]);
      *(float2*)&v_out[vb] = vo;
      *(unsigned int*)&v_out_b[vb] =
          (unsigned int)f2b(vo.x) | ((unsigned int)f2b(vo.y) << 16);
    }
  }
}

// ---------- v_norm from fused V buffer [N*3,256] (V1 = cols 0..127) ----------
__global__ __launch_bounds__(256) void vnorm_kernel(const float* __restrict__ V12,
                                                    unsigned short* __restrict__ vnb) {
  int idx = blockIdx.x * 256 + threadIdx.x;   // over N_NODES*32
  if (idx >= N_NODES * 32) return;
  int node = idx >> 5, c4 = (idx & 31) * 4;
  size_t b = (size_t)node * 768 + c4;
  float4 x = *(const float4*)&V12[b];
  float4 y = *(const float4*)&V12[b + 256];
  float4 zz = *(const float4*)&V12[b + 512];
  ushort4 o;
  o.x = f2b(sqrtf(x.x * x.x + y.x * y.x + zz.x * zz.x));
  o.y = f2b(sqrtf(x.y * x.y + y.y * y.y + zz.y * zz.y));
  o.z = f2b(sqrtf(x.z * x.z + y.z * y.z + zz.z * zz.z));
  o.w = f2b(sqrtf(x.w * x.w + y.w * y.w + zz.w * zz.w));
  *(ushort4*)&vnb[(size_t)node * 128 + c4] = o;
}

// ---------- per-layer update: s += a ; v = v*b + V2*c (V2 = cols 128..255) ----------
__global__ __launch_bounds__(256) void update_kernel(const float* __restrict__ s_msg,
                                                     const float* __restrict__ v_msg,
                                                     const float* __restrict__ u,
                                                     const float* __restrict__ V12,
                                                     float* __restrict__ s_out,
                                                     unsigned short* __restrict__ s_out_b,
                                                     float* __restrict__ v_out,
                                                     unsigned short* __restrict__ v_out_b) {
  int idx = blockIdx.x * 256 + threadIdx.x;   // over N_NODES*32
  if (idx >= N_NODES * 32) return;
  int node = idx >> 5, c4 = (idx & 31) * 4;
  size_t ub = (size_t)node * 384 + c4;
  float4 a = *(const float4*)&u[ub];
  float4 b = *(const float4*)&u[ub + 128];
  float4 cc = *(const float4*)&u[ub + 256];
  size_t sb = (size_t)node * 128 + c4;
  float4 sm = *(const float4*)&s_msg[sb];
  float4 so = make_float4(sm.x + a.x, sm.y + a.y, sm.z + a.z, sm.w + a.w);
  *(float4*)&s_out[sb] = so;
  ushort4 sob = {f2b(so.x), f2b(so.y), f2b(so.z), f2b(so.w)};
  *(ushort4*)&s_out_b[sb] = sob;
#pragma unroll
  for (int dd = 0; dd < 3; ++dd) {
    size_t vb = (size_t)node * 384 + dd * 128 + c4;
    size_t vbv = (size_t)node * 768 + dd * 256 + 128 + c4;
    float4 vm = *(const float4*)&v_msg[vb];
    float4 v2 = *(const float4*)&V12[vbv];
    float4 vo = make_float4(vm.x * b.x + v2.x * cc.x, vm.y * b.y + v2.y * cc.y,
                            vm.z * b.z + v2.z * cc.z, vm.w * b.w + v2.w * cc.w);
    *(float4*)&v_out[vb] = vo;
    ushort4 vob = {f2b(vo.x), f2b(vo.y), f2b(vo.z), f2b(vo.w)};
    *(ushort4*)&v_out_b[vb] = vob;
  }
}

// ---------- readout part 2: y = relu_h @ w2, pooled ----------
__global__ __launch_bounds__(256) void readout2_kernel(const float* __restrict__ ro_h,
                                                       const float* __restrict__ w2,
                                                       const int* __restrict__ batch,
                                                       float* __restrict__ pool,
                                                       float* __restrict__ cnt) {
  int node = blockIdx.x * 4 + (threadIdx.x >> 6);
  if (node >= N_NODES) return;
  int lane = threadIdx.x & 63;
  float y = ro_h[(size_t)node * 64 + lane] * w2[lane];
#pragma unroll
  for (int o = 32; o > 0; o >>= 1) y += __shfl_xor(y, o);
  if (lane == 0) {
    int b = batch[node];
    atomicAdd(&pool[b], y);
    atomicAdd(&cnt[b], 1.0f);
  }
}

__global__ void final_kernel(const float* __restrict__ pool,
                             const float* __restrict__ cnt,
                             const float* __restrict__ b2,
                             float* __restrict__ out) {
  int g = threadIdx.x;
  if (g < NGRAPH) out[g] = (pool[g] + cnt[g] * b2[0]) / fmaxf(cnt[g], 1.0f);
}

// ---------- host ----------
extern "C" void kernel_launch(void* const* d_in, const int* in_sizes, int n_in,
                              void* d_out, int out_size, void* d_ws, size_t ws_size,
                              hipStream_t stream) {
  const int*   z      = (const int*)d_in[0];
  const float* pos    = (const float*)d_in[1];
  const int*   esrc   = (const int*)d_in[2];
  const int*   edst   = esrc + N_EDGES;
  const int*   batch  = (const int*)d_in[3];
  const float* embed  = (const float*)d_in[4];
  const float* msg_w1 = (const float*)d_in[5];
  const float* msg_b1 = (const float*)d_in[6];
  const float* msg_w2 = (const float*)d_in[7];
  const float* msg_b2 = (const float*)d_in[8];
  const float* filt_w = (const float*)d_in[9];
  const float* filt_b = (const float*)d_in[10];
  const float* vec_w  = (const float*)d_in[11];
  const float* upd_w1 = (const float*)d_in[12];
  const float* upd_b1 = (const float*)d_in[13];
  const float* upd_w2 = (const float*)d_in[14];
  const float* upd_b2 = (const float*)d_in[15];
  const float* ro_w1  = (const float*)d_in[16];
  const float* ro_b1  = (const float*)d_in[17];
  const float* ro_w2  = (const float*)d_in[18];
  const float* ro_b2  = (const float*)d_in[19];
  (void)in_sizes; (void)n_in; (void)out_size;

  void* wsp = nullptr;
  if (hipGetSymbolAddress(&wsp, HIP_SYMBOL(g_ws)) != hipSuccess || wsp == nullptr) {
    wsp = d_ws;
  }
  char* wsb = (char*)wsp;
  size_t o = 0;
  auto alloc = [&](size_t bytes) -> void* {
    void* p = wsb + o;
    o += (bytes + 255) & ~(size_t)255;
    return p;
  };
  float4* geom   = (float4*)alloc(sizeof(float4) * N_EDGES);
  float* rbf     = (float*)alloc(4ull * N_EDGES * 20);
  int* csr_off   = (int*)alloc(4ull * (N_NODES + 1));
  int* deg       = (int*)alloc(4ull * N_NODES);
  int* cursor    = (int*)alloc(4ull * N_NODES);
  int* csr_eid   = (int*)alloc(4ull * N_EDGES);
  float* sA      = (float*)alloc(4ull * N_NODES * 128);
  float* vA      = (float*)alloc(4ull * N_NODES * 384);
  float* sB      = (float*)alloc(4ull * N_NODES * 128);
  float* vB      = (float*)alloc(4ull * N_NODES * 384);
  float* ubuf    = (float*)alloc(4ull * N_NODES * 384);
  float* Vbuf    = (float*)alloc(4ull * N_NODES * 768);   // fused V1|V2
  float* ro_h    = (float*)alloc(4ull * N_NODES * 64);
  unsigned short* s_all_b = (unsigned short*)alloc(2ull * N_NODES * 384);
  unsigned short* sAb    = (unsigned short*)alloc(2ull * N_NODES * 128);
  unsigned short* sBb    = (unsigned short*)alloc(2ull * N_NODES * 128);
  unsigned short* vAb    = (unsigned short*)alloc(2ull * N_NODES * 384);
  unsigned short* vBb    = (unsigned short*)alloc(2ull * N_NODES * 384);
  unsigned short* vnb    = (unsigned short*)alloc(2ull * N_NODES * 128);
  unsigned short* hidden = (unsigned short*)alloc(2ull * N_NODES * 128);
  unsigned short* wb_m1  = (unsigned short*)alloc(2ull * NLAY * 128 * 128);
  unsigned short* wb_m2  = (unsigned short*)alloc(2ull * NLAY * 128 * 384);
  unsigned short* wb_vw  = (unsigned short*)alloc(2ull * NLAY * 128 * 256);
  unsigned short* wb_u1  = (unsigned short*)alloc(2ull * NLAY * 256 * 128);
  unsigned short* wb_u2  = (unsigned short*)alloc(2ull * NLAY * 128 * 384);
  unsigned short* wb_fw  = (unsigned short*)alloc(2ull * NLAY * 50 * 384);
  unsigned short* wb_ro  = (unsigned short*)alloc(2ull * 128 * 64);
  float* pool    = (float*)alloc(4ull * NGRAPH);
  float* cnt     = (float*)alloc(4ull * NGRAPH);

  if (wsb == (char*)d_ws && o > ws_size) return;

  hipMemsetAsync(deg, 0, 4ull * N_NODES, stream);
  hipMemsetAsync(cursor, 0, 4ull * N_NODES, stream);
  hipMemsetAsync(pool, 0, 4ull * NGRAPH, stream);
  hipMemsetAsync(cnt, 0, 4ull * NGRAPH, stream);

  auto cvt = [&](const float* in, unsigned short* out, int n) {
    cvt_kernel<<<(n + 255) / 256, 256, 0, stream>>>(in, out, n);
  };
  cvt(msg_w1, wb_m1, NLAY * 128 * 128);
  cvt(msg_w2, wb_m2, NLAY * 128 * 384);
  cvt(vec_w,  wb_vw, NLAY * 128 * 256);
  cvt(upd_w1, wb_u1, NLAY * 256 * 128);
  cvt(upd_w2, wb_u2, NLAY * 128 * 384);
  cvt(filt_w, wb_fw, NLAY * 50 * 384);
  cvt(ro_w1,  wb_ro, 128 * 64);

  geom_kernel<<<(N_EDGES + 255) / 256, 256, 0, stream>>>(esrc, edst, pos, geom);
  rbf_kernel<<<(N_EDGES * 32 + 255) / 256, 256, 0, stream>>>(geom, rbf);
  hist_kernel<<<(N_EDGES + 255) / 256, 256, 0, stream>>>(edst, deg);
  scan_kernel<<<1, 1024, 0, stream>>>(deg, csr_off, N_NODES);
  fill_kernel<<<(N_EDGES + 255) / 256, 256, 0, stream>>>(edst, csr_off, cursor, csr_eid);
  init_kernel<<<(N_NODES * 384 + 255) / 256, 256, 0, stream>>>(z, embed, sA, sAb, vA,
                                                               vAb);

  const int BIG = 1 << 30;
  for (int i = 0; i < NLAY; ++i) {
    const float* mb1 = msg_b1 + (size_t)i * 128;
    const float* mb2 = msg_b2 + (size_t)i * 384;
    const float* fbv = filt_b + (size_t)i * 384;
    const float* ub1 = upd_b1 + (size_t)i * 128;
    const float* ub2 = upd_b2 + (size_t)i * 384;
    const unsigned short* m1 = wb_m1 + (size_t)i * 128 * 128;
    const unsigned short* m2 = wb_m2 + (size_t)i * 128 * 384;
    const unsigned short* vw = wb_vw + (size_t)i * 128 * 256;
    const unsigned short* u1 = wb_u1 + (size_t)i * 256 * 128;
    const unsigned short* u2 = wb_u2 + (size_t)i * 128 * 384;
    const unsigned short* fwb = wb_fw + (size_t)i * 50 * 384;

    gemm_bf16<<<dim3(2, 625), 256, 0, stream>>>(sAb, 128, sAb, 128, BIG, m1, 128, mb1,
                                                hidden, 128, 128, 1, 1);
    gemm_bf16<<<dim3(6, 625), 256, 0, stream>>>(hidden, 128, hidden, 128, BIG, m2, 384,
                                                mb2, s_all_b, 384, 128, 0, 1);
    msg_kernel<<<N_NODES / 2, 256, 0, stream>>>(csr_off, csr_eid, esrc, geom, rbf,
                                                s_all_b, fwb, fbv, sA, vA, vAb,
                                                sB, sBb, vB, vBb);
    gemm_bf16<<<dim3(4, 1875), 256, 0, stream>>>(vBb, 128, vBb, 128, BIG, vw, 256,
                                                 nullptr, Vbuf, 256, 128, 0, 0);
    vnorm_kernel<<<(N_NODES * 32 + 255) / 256, 256, 0, stream>>>(Vbuf, vnb);
    gemm_bf16<<<dim3(2, 625), 256, 0, stream>>>(sBb, 128, vnb, 128, 128, u1, 128, ub1,
                                                hidden, 128, 256, 1, 1);
    gemm_bf16<<<dim3(6, 625), 256, 0, stream>>>(hidden, 128, hidden, 128, BIG, u2, 384,
                                                ub2, ubuf, 384, 128, 0, 0);
    update_kernel<<<(N_NODES * 32 + 255) / 256, 256, 0, stream>>>(sB, vB, ubuf, Vbuf,
                                                                  sA, sAb, vA, vAb);
  }

  gemm_bf16<<<dim3(1, 625), 256, 0, stream>>>(sAb, 128, sAb, 128, BIG, wb_ro, 64, ro_b1,
                                              ro_h, 64, 128, 1, 0);
  readout2_kernel<<<N_NODES / 4, 256, 0, stream>>>(ro_h, ro_w2, batch, pool, cnt);
  final_kernel<<<1, 256, 0, stream>>>(pool, cnt, ro_b2, (float*)d_out);
}

// Round 8
// 1518.766 us; speedup vs baseline: 1.6953x; 1.6953x over previous
//
#include <hip/hip_runtime.h>
#include <hip/hip_bf16.h>
#include <math.h>

// PaiNN forward, MI355X. Round 8: revert round-7's unconditional-17 RBF bug
// (data-dependent g-loop restored — ~80% of edges have ZERO in-range
// gaussians); keep bf16 filt_w + uint gathers; add 2-way edge-parity split
// (2 waves/node, LDS combine). GEMM: BM=128 tile, packed b32 B-staging.

#define N_NODES 40000
#define N_EDGES 400000
#define NGAUSS  50
#define NLAY    3
#define NGRAPH  256

#define WS_BYTES (512ull * 1024 * 1024)
__device__ __align__(256) unsigned char g_ws[WS_BYTES];

typedef __attribute__((ext_vector_type(8))) short short8;
typedef __attribute__((ext_vector_type(4))) float f32x4;

__device__ __forceinline__ float relu_f(float x) { return fmaxf(x, 0.f); }
__device__ __forceinline__ unsigned short f2b(float x) {
  __hip_bfloat16 h = __float2bfloat16(x);
  return *reinterpret_cast<unsigned short*>(&h);
}
__device__ __forceinline__ float b2f_lo(unsigned int u) {
  return __uint_as_float(u << 16);
}
__device__ __forceinline__ float b2f_hi(unsigned int u) {
  return __uint_as_float(u & 0xffff0000u);
}

// ---------- f32 -> bf16 elementwise ----------
__global__ __launch_bounds__(256) void cvt_kernel(const float* __restrict__ in,
                                                  unsigned short* __restrict__ out,
                                                  int n) {
  int i = blockIdx.x * 256 + threadIdx.x;
  if (i < n) out[i] = f2b(in[i]);
}

// ---------- geometry ----------
__global__ __launch_bounds__(256) void geom_kernel(const int* __restrict__ src,
                                                   const int* __restrict__ dst,
                                                   const float* __restrict__ pos,
                                                   float4* __restrict__ geom) {
  int e = blockIdx.x * 256 + threadIdx.x;
  if (e >= N_EDGES) return;
  int s = src[e], d = dst[e];
  float dx = pos[s * 3 + 0] - pos[d * 3 + 0];
  float dy = pos[s * 3 + 1] - pos[d * 3 + 1];
  float dz = pos[s * 3 + 2] - pos[d * 3 + 2];
  float dist = sqrtf(dx * dx + dy * dy + dz * dz);
  float inv = 1.f / (dist + 1e-8f);
  geom[e] = make_float4(dx * inv, dy * inv, dz * inv, dist);
}

// ---------- CSR build ----------
__global__ __launch_bounds__(256) void hist_kernel(const int* __restrict__ dst,
                                                   int* __restrict__ deg) {
  int e = blockIdx.x * 256 + threadIdx.x;
  if (e < N_EDGES) atomicAdd(&deg[dst[e]], 1);
}

__global__ __launch_bounds__(1024) void scan_kernel(const int* __restrict__ deg,
                                                    int* __restrict__ off, int n) {
  __shared__ int wsum[16];
  __shared__ int ctot;
  int t = threadIdx.x, lane = t & 63, w = t >> 6;
  int carry = 0;
  for (int base = 0; base < n; base += 1024) {
    int i = base + t;
    int v = (i < n) ? deg[i] : 0;
    int x = v;
#pragma unroll
    for (int dd = 1; dd < 64; dd <<= 1) {
      int y = __shfl_up(x, dd);
      if (lane >= dd) x += y;
    }
    if (lane == 63) wsum[w] = x;
    __syncthreads();
    if (w == 0 && lane < 16) {
      int self = wsum[lane];
      int xs = self;
#pragma unroll
      for (int dd = 1; dd < 16; dd <<= 1) {
        int y = __shfl_up(xs, dd);
        if (lane >= dd) xs += y;
      }
      wsum[lane] = xs - self;
      if (lane == 15) ctot = xs;
    }
    __syncthreads();
    if (i < n) off[i] = carry + wsum[w] + (x - v);
    carry += ctot;
    __syncthreads();
  }
  if (t == 0) off[n] = carry;
}

__global__ __launch_bounds__(256) void fill_kernel(const int* __restrict__ dst,
                                                   const int* __restrict__ off,
                                                   int* __restrict__ cursor,
                                                   int* __restrict__ eid) {
  int e = blockIdx.x * 256 + threadIdx.x;
  if (e >= N_EDGES) return;
  int d = dst[e];
  int p = atomicAdd(&cursor[d], 1);
  eid[off[d] + p] = e;
}

// ---------- init: s = embed[z] (f32 + bf16), v = 0 (f32 + bf16) ----------
__global__ __launch_bounds__(256) void init_kernel(const int* __restrict__ z,
                                                   const float* __restrict__ embed,
                                                   float* __restrict__ s,
                                                   unsigned short* __restrict__ sb,
                                                   float* __restrict__ v,
                                                   unsigned short* __restrict__ vb) {
  int idx = blockIdx.x * 256 + threadIdx.x;
  if (idx < N_NODES * 384) { v[idx] = 0.f; vb[idx] = 0; }
  if (idx < N_NODES * 128) {
    int node = idx >> 7, c = idx & 127;
    float val = embed[z[node] * 128 + c];
    s[idx] = val;
    sb[idx] = f2b(val);
  }
}

// ---------- bf16 MFMA GEMM: BM=128, BN=64, 4 waves (each 32 rows) ----------
// B staged transposed in LDS as packed uint k-pairs (b32 writes).
#define KMAX 256
__global__ __launch_bounds__(256) void gemm_bf16(
    const unsigned short* __restrict__ A1, int lda1,
    const unsigned short* __restrict__ A2, int lda2, int kSplit,
    const unsigned short* __restrict__ B, int ldb,
    const float* __restrict__ bias,
    void* __restrict__ C, int ldc, int M, int K, int doRelu, int outBf16) {
  __shared__ unsigned int Bt32[64][KMAX / 2 + 4];  // row 528 B (16B mult)
  int t = threadIdx.x;
  int lane = t & 63, w = t >> 6;
  int n0 = blockIdx.x * 64, m0 = blockIdx.y * 128;

  // stage B[k][n0..n0+63]: pack rows (k, k+1) of col c into one uint
  {
    int c4 = (t & 15) * 4;
    for (int k = (t >> 4) * 2; k < K; k += 32) {
      uint2 va = *(const uint2*)&B[(size_t)k * ldb + n0 + c4];
      uint2 vb = *(const uint2*)&B[(size_t)(k + 1) * ldb + n0 + c4];
      Bt32[c4 + 0][k >> 1] = (va.x & 0xffffu) | (vb.x << 16);
      Bt32[c4 + 1][k >> 1] = (va.x >> 16) | (vb.x & 0xffff0000u);
      Bt32[c4 + 2][k >> 1] = (va.y & 0xffffu) | (vb.y << 16);
      Bt32[c4 + 3][k >> 1] = (va.y >> 16) | (vb.y & 0xffff0000u);
    }
  }
  __syncthreads();

  int row = lane & 15;   // A row / B col / D col within 16
  int kg = lane >> 4;    // 0..3

  f32x4 acc[2][4];
#pragma unroll
  for (int rf = 0; rf < 2; ++rf)
#pragma unroll
    for (int nf = 0; nf < 4; ++nf) acc[rf][nf] = (f32x4){0.f, 0.f, 0.f, 0.f};

  for (int ks = 0; ks < K; ks += 32) {
    int kk = ks + kg * 8;
    short8 af[2];
#pragma unroll
    for (int rf = 0; rf < 2; ++rf) {
      int mrow = m0 + w * 32 + rf * 16 + row;
      if (mrow >= M) mrow = M - 1;  // safe clamp; store is guarded
      const unsigned short* Ap;
      int kloc;
      if (kk < kSplit) { Ap = A1 + (size_t)mrow * lda1; kloc = kk; }
      else             { Ap = A2 + (size_t)mrow * lda2; kloc = kk - kSplit; }
      af[rf] = *(const short8*)&Ap[kloc];
    }
#pragma unroll
    for (int nf = 0; nf < 4; ++nf) {
      short8 bf = *(const short8*)((const unsigned short*)Bt32[nf * 16 + row] + kk);
#pragma unroll
      for (int rf = 0; rf < 2; ++rf)
        acc[rf][nf] = __builtin_amdgcn_mfma_f32_16x16x32_bf16(af[rf], bf,
                                                              acc[rf][nf], 0, 0, 0);
    }
  }

#pragma unroll
  for (int rf = 0; rf < 2; ++rf)
#pragma unroll
    for (int nf = 0; nf < 4; ++nf)
#pragma unroll
      for (int r = 0; r < 4; ++r) {
        int gr = m0 + w * 32 + rf * 16 + kg * 4 + r;
        int gc = n0 + nf * 16 + row;
        if (gr < M) {
          float val = acc[rf][nf][r] + (bias ? bias[gc] : 0.f);
          if (doRelu) val = relu_f(val);
          if (outBf16) ((unsigned short*)C)[(size_t)gr * ldc + gc] = f2b(val);
          else         ((float*)C)[(size_t)gr * ldc + gc] = val;
        }
      }
}

// ---------- accumulate one edge's contribution ----------
__device__ __forceinline__ void accum_edge(const unsigned int (&sa)[3],
                                           const unsigned int (&vv)[3],
                                           const float (&w)[3][2],
                                           float gx, float gy, float gz,
                                           float (&ds)[2], float (&dv)[3][2]) {
  float gt[3][2];
#pragma unroll
  for (int jj = 0; jj < 3; ++jj) {
    gt[jj][0] = b2f_lo(sa[jj]) * w[jj][0];
    gt[jj][1] = b2f_hi(sa[jj]) * w[jj][1];
  }
  ds[0] += gt[0][0];
  ds[1] += gt[0][1];
  float dn[3] = {gx, gy, gz};
#pragma unroll
  for (int dd = 0; dd < 3; ++dd) {
    dv[dd][0] = fmaf(b2f_lo(vv[dd]), gt[1][0], fmaf(dn[dd], gt[2][0], dv[dd][0]));
    dv[dd][1] = fmaf(b2f_hi(vv[dd]), gt[1][1], fmaf(dn[dd], gt[2][1], dv[dd][1]));
  }
}

// ---------- fused edge message: 2 waves per node (parity), simple body ----------
// Block = 4 waves = 2 nodes. Wave (p,nl): node = blockIdx.x*2+nl, edges
// e0+p, e0+p+2, ... Lane owns channels {2*lane, 2*lane+1}. LDS combine.
// Data-dependent gaussian loop: ZERO iterations for out-of-range edges.
__global__ __launch_bounds__(256) void msg_kernel(const int* __restrict__ off,
                                                  const int* __restrict__ eid_arr,
                                                  const int* __restrict__ src_arr,
                                                  const float4* __restrict__ geom,
                                                  const unsigned short* __restrict__ s_all_b,
                                                  const unsigned short* __restrict__ fwb,
                                                  const float* __restrict__ fb,
                                                  const float* __restrict__ s_in,
                                                  const float* __restrict__ v_in,
                                                  const unsigned short* __restrict__ v_in_b,
                                                  float* __restrict__ s_out,
                                                  unsigned short* __restrict__ s_out_b,
                                                  float* __restrict__ v_out,
                                                  unsigned short* __restrict__ v_out_b) {
  __shared__ float cmb[2][512];
  int t = threadIdx.x;
  int lane = t & 63, w = t >> 6;
  int p = w & 1, nl = w >> 1;
  int node = blockIdx.x * 2 + nl;
  int c2 = lane * 2;
  const float DELTA = 6.0f / 49.0f;
  const float INVD = 49.0f / 6.0f;
  const float CO = -0.5f * INVD * INVD;
  float fbr[3][2];
#pragma unroll
  for (int jj = 0; jj < 3; ++jj) {
    float2 f = *(const float2*)&fb[jj * 128 + c2];
    fbr[jj][0] = f.x; fbr[jj][1] = f.y;
  }
  float ds[2] = {0.f, 0.f};
  float dv[3][2] = {{0.f}};
  int e0 = off[node], e1 = off[node + 1];

  for (int q = e0 + p; q < e1; q += 2) {
    int e = eid_arr[q];
    int s = src_arr[e];
    float4 gm = geom[e];
    float d = gm.w;
    float wv[3][2];
#pragma unroll
    for (int jj = 0; jj < 3; ++jj) { wv[jj][0] = fbr[jj][0]; wv[jj][1] = fbr[jj][1]; }
    int glo = max(0, (int)ceilf(d * INVD - 8.f));
    int ghi = min(NGAUSS - 1, (int)floorf(d * INVD + 8.f));
    for (int g = glo; g <= ghi; ++g) {
      float diff = d - g * DELTA;
      float r = __expf(CO * diff * diff);
      const unsigned short* fr = fwb + (size_t)g * 384 + c2;
#pragma unroll
      for (int jj = 0; jj < 3; ++jj) {
        unsigned int f = *(const unsigned int*)&fr[jj * 128];
        wv[jj][0] = fmaf(r, b2f_lo(f), wv[jj][0]);
        wv[jj][1] = fmaf(r, b2f_hi(f), wv[jj][1]);
      }
    }
    const unsigned short* pas = s_all_b + (size_t)s * 384 + c2;
    const unsigned short* pav = v_in_b + (size_t)s * 384 + c2;
    unsigned int a_s[3] = {*(const unsigned int*)&pas[0],
                           *(const unsigned int*)&pas[128],
                           *(const unsigned int*)&pas[256]};
    unsigned int a_v[3] = {*(const unsigned int*)&pav[0],
                           *(const unsigned int*)&pav[128],
                           *(const unsigned int*)&pav[256]};
    accum_edge(a_s, a_v, wv, gm.x, gm.y, gm.z, ds, dv);
  }

  // combine parity partials via LDS: p0 writes, p1 adds + final store
  if (p == 0) {
    cmb[nl][c2] = ds[0];
    cmb[nl][c2 + 1] = ds[1];
#pragma unroll
    for (int dd = 0; dd < 3; ++dd) {
      cmb[nl][128 + dd * 128 + c2] = dv[dd][0];
      cmb[nl][128 + dd * 128 + c2 + 1] = dv[dd][1];
    }
  }
  __syncthreads();
  if (p == 1) {
    ds[0] += cmb[nl][c2];
    ds[1] += cmb[nl][c2 + 1];
#pragma unroll
    for (int dd = 0; dd < 3; ++dd) {
      dv[dd][0] += cmb[nl][128 + dd * 128 + c2];
      dv[dd][1] += cmb[nl][128 + dd * 128 + c2 + 1];
    }
    size_t sb = (size_t)node * 128 + c2;
    float2 si = *(const float2*)&s_in[sb];
    float2 so = make_float2(si.x + ds[0], si.y + ds[1]);
    *(float2*)&s_out[sb] = so;
    *(unsigned int*)&s_out_b[sb] =
        (unsigned int)f2b(so.x) | ((unsigned int)f2b(so.y) << 16);
#pragma unroll
    for (int dd = 0; dd < 3; ++dd) {
      size_t vb = (size_t)node * 384 + dd * 128 + c2;
      float2 vi = *(const float2*)&v_in[vb];
      float2 vo = make_float2(vi.x + dv[dd][0], vi.y + dv[dd][1]);
      *(float2*)&v_out[vb] = vo;
      *(unsigned int*)&v_out_b[vb] =
          (unsigned int)f2b(vo.x) | ((unsigned int)f2b(vo.y) << 16);
    }
  }
}

// ---------- v_norm from fused V buffer [N*3,256] (V1 = cols 0..127) ----------
__global__ __launch_bounds__(256) void vnorm_kernel(const float* __restrict__ V12,
                                                    unsigned short* __restrict__ vnb) {
  int idx = blockIdx.x * 256 + threadIdx.x;   // over N_NODES*32
  if (idx >= N_NODES * 32) return;
  int node = idx >> 5, c4 = (idx & 31) * 4;
  size_t b = (size_t)node * 768 + c4;
  float4 x = *(const float4*)&V12[b];
  float4 y = *(const float4*)&V12[b + 256];
  float4 zz = *(const float4*)&V12[b + 512];
  ushort4 o;
  o.x = f2b(sqrtf(x.x * x.x + y.x * y.x + zz.x * zz.x));
  o.y = f2b(sqrtf(x.y * x.y + y.y * y.y + zz.y * zz.y));
  o.z = f2b(sqrtf(x.z * x.z + y.z * y.z + zz.z * zz.z));
  o.w = f2b(sqrtf(x.w * x.w + y.w * y.w + zz.w * zz.w));
  *(ushort4*)&vnb[(size_t)node * 128 + c4] = o;
}

// ---------- per-layer update: s += a ; v = v*b + V2*c (V2 = cols 128..255) ----------
__global__ __launch_bounds__(256) void update_kernel(const float* __restrict__ s_msg,
                                                     const float* __restrict__ v_msg,
                                                     const float* __restrict__ u,
                                                     const float* __restrict__ V12,
                                                     float* __restrict__ s_out,
                                                     unsigned short* __restrict__ s_out_b,
                                                     float* __restrict__ v_out,
                                                     unsigned short* __restrict__ v_out_b) {
  int idx = blockIdx.x * 256 + threadIdx.x;   // over N_NODES*32
  if (idx >= N_NODES * 32) return;
  int node = idx >> 5, c4 = (idx & 31) * 4;
  size_t ub = (size_t)node * 384 + c4;
  float4 a = *(const float4*)&u[ub];
  float4 b = *(const float4*)&u[ub + 128];
  float4 cc = *(const float4*)&u[ub + 256];
  size_t sb = (size_t)node * 128 + c4;
  float4 sm = *(const float4*)&s_msg[sb];
  float4 so = make_float4(sm.x + a.x, sm.y + a.y, sm.z + a.z, sm.w + a.w);
  *(float4*)&s_out[sb] = so;
  ushort4 sob = {f2b(so.x), f2b(so.y), f2b(so.z), f2b(so.w)};
  *(ushort4*)&s_out_b[sb] = sob;
#pragma unroll
  for (int dd = 0; dd < 3; ++dd) {
    size_t vb = (size_t)node * 384 + dd * 128 + c4;
    size_t vbv = (size_t)node * 768 + dd * 256 + 128 + c4;
    float4 vm = *(const float4*)&v_msg[vb];
    float4 v2 = *(const float4*)&V12[vbv];
    float4 vo = make_float4(vm.x * b.x + v2.x * cc.x, vm.y * b.y + v2.y * cc.y,
                            vm.z * b.z + v2.z * cc.z, vm.w * b.w + v2.w * cc.w);
    *(float4*)&v_out[vb] = vo;
    ushort4 vob = {f2b(vo.x), f2b(vo.y), f2b(vo.z), f2b(vo.w)};
    *(ushort4*)&v_out_b[vb] = vob;
  }
}

// ---------- readout part 2: y = relu_h @ w2, pooled ----------
__global__ __launch_bounds__(256) void readout2_kernel(const float* __restrict__ ro_h,
                                                       const float* __restrict__ w2,
                                                       const int* __restrict__ batch,
                                                       float* __restrict__ pool,
                                                       float* __restrict__ cnt) {
  int node = blockIdx.x * 4 + (threadIdx.x >> 6);
  if (node >= N_NODES) return;
  int lane = threadIdx.x & 63;
  float y = ro_h[(size_t)node * 64 + lane] * w2[lane];
#pragma unroll
  for (int o = 32; o > 0; o >>= 1) y += __shfl_xor(y, o);
  if (lane == 0) {
    int b = batch[node];
    atomicAdd(&pool[b], y);
    atomicAdd(&cnt[b], 1.0f);
  }
}

__global__ void final_kernel(const float* __restrict__ pool,
                             const float* __restrict__ cnt,
                             const float* __restrict__ b2,
                             float* __restrict__ out) {
  int g = threadIdx.x;
  if (g < NGRAPH) out[g] = (pool[g] + cnt[g] * b2[0]) / fmaxf(cnt[g], 1.0f);
}

// ---------- host ----------
extern "C" void kernel_launch(void* const* d_in, const int* in_sizes, int n_in,
                              void* d_out, int out_size, void* d_ws, size_t ws_size,
                              hipStream_t stream) {
  const int*   z      = (const int*)d_in[0];
  const float* pos    = (const float*)d_in[1];
  const int*   esrc   = (const int*)d_in[2];
  const int*   edst   = esrc + N_EDGES;
  const int*   batch  = (const int*)d_in[3];
  const float* embed  = (const float*)d_in[4];
  const float* msg_w1 = (const float*)d_in[5];
  const float* msg_b1 = (const float*)d_in[6];
  const float* msg_w2 = (const float*)d_in[7];
  const float* msg_b2 = (const float*)d_in[8];
  const float* filt_w = (const float*)d_in[9];
  const float* filt_b = (const float*)d_in[10];
  const float* vec_w  = (const float*)d_in[11];
  const float* upd_w1 = (const float*)d_in[12];
  const float* upd_b1 = (const float*)d_in[13];
  const float* upd_w2 = (const float*)d_in[14];
  const float* upd_b2 = (const float*)d_in[15];
  const float* ro_w1  = (const float*)d_in[16];
  const float* ro_b1  = (const float*)d_in[17];
  const float* ro_w2  = (const float*)d_in[18];
  const float* ro_b2  = (const float*)d_in[19];
  (void)in_sizes; (void)n_in; (void)out_size;

  void* wsp = nullptr;
  if (hipGetSymbolAddress(&wsp, HIP_SYMBOL(g_ws)) != hipSuccess || wsp == nullptr) {
    wsp = d_ws;
  }
  char* wsb = (char*)wsp;
  size_t o = 0;
  auto alloc = [&](size_t bytes) -> void* {
    void* p = wsb + o;
    o += (bytes + 255) & ~(size_t)255;
    return p;
  };
  float4* geom   = (float4*)alloc(sizeof(float4) * N_EDGES);
  int* csr_off   = (int*)alloc(4ull * (N_NODES + 1));
  int* deg       = (int*)alloc(4ull * N_NODES);
  int* cursor    = (int*)alloc(4ull * N_NODES);
  int* csr_eid   = (int*)alloc(4ull * N_EDGES);
  float* sA      = (float*)alloc(4ull * N_NODES * 128);
  float* vA      = (float*)alloc(4ull * N_NODES * 384);
  float* sB      = (float*)alloc(4ull * N_NODES * 128);
  float* vB      = (float*)alloc(4ull * N_NODES * 384);
  float* ubuf    = (float*)alloc(4ull * N_NODES * 384);
  float* Vbuf    = (float*)alloc(4ull * N_NODES * 768);   // fused V1|V2
  float* ro_h    = (float*)alloc(4ull * N_NODES * 64);
  unsigned short* s_all_b = (unsigned short*)alloc(2ull * N_NODES * 384);
  unsigned short* sAb    = (unsigned short*)alloc(2ull * N_NODES * 128);
  unsigned short* sBb    = (unsigned short*)alloc(2ull * N_NODES * 128);
  unsigned short* vAb    = (unsigned short*)alloc(2ull * N_NODES * 384);
  unsigned short* vBb    = (unsigned short*)alloc(2ull * N_NODES * 384);
  unsigned short* vnb    = (unsigned short*)alloc(2ull * N_NODES * 128);
  unsigned short* hidden = (unsigned short*)alloc(2ull * N_NODES * 128);
  unsigned short* wb_m1  = (unsigned short*)alloc(2ull * NLAY * 128 * 128);
  unsigned short* wb_m2  = (unsigned short*)alloc(2ull * NLAY * 128 * 384);
  unsigned short* wb_vw  = (unsigned short*)alloc(2ull * NLAY * 128 * 256);
  unsigned short* wb_u1  = (unsigned short*)alloc(2ull * NLAY * 256 * 128);
  unsigned short* wb_u2  = (unsigned short*)alloc(2ull * NLAY * 128 * 384);
  unsigned short* wb_fw  = (unsigned short*)alloc(2ull * NLAY * 50 * 384);
  unsigned short* wb_ro  = (unsigned short*)alloc(2ull * 128 * 64);
  float* pool    = (float*)alloc(4ull * NGRAPH);
  float* cnt     = (float*)alloc(4ull * NGRAPH);

  if (wsb == (char*)d_ws && o > ws_size) return;

  hipMemsetAsync(deg, 0, 4ull * N_NODES, stream);
  hipMemsetAsync(cursor, 0, 4ull * N_NODES, stream);
  hipMemsetAsync(pool, 0, 4ull * NGRAPH, stream);
  hipMemsetAsync(cnt, 0, 4ull * NGRAPH, stream);

  auto cvt = [&](const float* in, unsigned short* out, int n) {
    cvt_kernel<<<(n + 255) / 256, 256, 0, stream>>>(in, out, n);
  };
  cvt(msg_w1, wb_m1, NLAY * 128 * 128);
  cvt(msg_w2, wb_m2, NLAY * 128 * 384);
  cvt(vec_w,  wb_vw, NLAY * 128 * 256);
  cvt(upd_w1, wb_u1, NLAY * 256 * 128);
  cvt(upd_w2, wb_u2, NLAY * 128 * 384);
  cvt(filt_w, wb_fw, NLAY * 50 * 384);
  cvt(ro_w1,  wb_ro, 128 * 64);

  geom_kernel<<<(N_EDGES + 255) / 256, 256, 0, stream>>>(esrc, edst, pos, geom);
  hist_kernel<<<(N_EDGES + 255) / 256, 256, 0, stream>>>(edst, deg);
  scan_kernel<<<1, 1024, 0, stream>>>(deg, csr_off, N_NODES);
  fill_kernel<<<(N_EDGES + 255) / 256, 256, 0, stream>>>(edst, csr_off, cursor, csr_eid);
  init_kernel<<<(N_NODES * 384 + 255) / 256, 256, 0, stream>>>(z, embed, sA, sAb, vA,
                                                               vAb);

  const int BIG = 1 << 30;
  const int GY40 = (N_NODES + 127) / 128;        // 313
  const int GY120 = (N_NODES * 3 + 127) / 128;   // 938
  for (int i = 0; i < NLAY; ++i) {
    const float* mb1 = msg_b1 + (size_t)i * 128;
    const float* mb2 = msg_b2 + (size_t)i * 384;
    const float* fbv = filt_b + (size_t)i * 384;
    const float* ub1 = upd_b1 + (size_t)i * 128;
    const float* ub2 = upd_b2 + (size_t)i * 384;
    const unsigned short* m1 = wb_m1 + (size_t)i * 128 * 128;
    const unsigned short* m2 = wb_m2 + (size_t)i * 128 * 384;
    const unsigned short* vw = wb_vw + (size_t)i * 128 * 256;
    const unsigned short* u1 = wb_u1 + (size_t)i * 256 * 128;
    const unsigned short* u2 = wb_u2 + (size_t)i * 128 * 384;
    const unsigned short* fwb = wb_fw + (size_t)i * 50 * 384;

    gemm_bf16<<<dim3(2, GY40), 256, 0, stream>>>(sAb, 128, sAb, 128, BIG, m1, 128, mb1,
                                                 hidden, 128, N_NODES, 128, 1, 1);
    gemm_bf16<<<dim3(6, GY40), 256, 0, stream>>>(hidden, 128, hidden, 128, BIG, m2, 384,
                                                 mb2, s_all_b, 384, N_NODES, 128, 0, 1);
    msg_kernel<<<N_NODES / 2, 256, 0, stream>>>(csr_off, csr_eid, esrc, geom,
                                                s_all_b, fwb, fbv, sA, vA, vAb,
                                                sB, sBb, vB, vBb);
    gemm_bf16<<<dim3(4, GY120), 256, 0, stream>>>(vBb, 128, vBb, 128, BIG, vw, 256,
                                                  nullptr, Vbuf, 256, N_NODES * 3, 128,
                                                  0, 0);
    vnorm_kernel<<<(N_NODES * 32 + 255) / 256, 256, 0, stream>>>(Vbuf, vnb);
    gemm_bf16<<<dim3(2, GY40), 256, 0, stream>>>(sBb, 128, vnb, 128, 128, u1, 128, ub1,
                                                 hidden, 128, N_NODES, 256, 1, 1);
    gemm_bf16<<<dim3(6, GY40), 256, 0, stream>>>(hidden, 128, hidden, 128, BIG, u2, 384,
                                                 ub2, ubuf, 384, N_NODES, 128, 0, 0);
    update_kernel<<<(N_NODES * 32 + 255) / 256, 256, 0, stream>>>(sB, vB, ubuf, Vbuf,
                                                                  sA, sAb, vA, vAb);
  }

  gemm_bf16<<<dim3(1, GY40), 256, 0, stream>>>(sAb, 128, sAb, 128, BIG, wb_ro, 64,
                                               ro_b1, ro_h, 64, N_NODES, 128, 1, 0);
  readout2_kernel<<<N_NODES / 4, 256, 0, stream>>>(ro_h, ro_w2, batch, pool, cnt);
  final_kernel<<<1, 256, 0, stream>>>(pool, cnt, ro_b2, (float*)d_out);
}

// Round 9
// 1253.345 us; speedup vs baseline: 2.0543x; 1.2118x over previous
//
#include <hip/hip_runtime.h>
#include <hip/hip_bf16.h>
#include <math.h>

// PaiNN forward, MI355X. Round 9: bf16-only v-state + bf16 V12/u buffers
// (cuts ~380 MB/layer of f32 traffic); msg_kernel back to simple
// wave-per-node body (parity split was neutral-negative). s stays f32.

#define N_NODES 40000
#define N_EDGES 400000
#define NGAUSS  50
#define NLAY    3
#define NGRAPH  256

#define WS_BYTES (448ull * 1024 * 1024)
__device__ __align__(256) unsigned char g_ws[WS_BYTES];

typedef __attribute__((ext_vector_type(8))) short short8;
typedef __attribute__((ext_vector_type(4))) float f32x4;

__device__ __forceinline__ float relu_f(float x) { return fmaxf(x, 0.f); }
__device__ __forceinline__ unsigned short f2b(float x) {
  __hip_bfloat16 h = __float2bfloat16(x);
  return *reinterpret_cast<unsigned short*>(&h);
}
__device__ __forceinline__ float b2f(unsigned short u) {
  return __uint_as_float(((unsigned int)u) << 16);
}
__device__ __forceinline__ float b2f_lo(unsigned int u) {
  return __uint_as_float(u << 16);
}
__device__ __forceinline__ float b2f_hi(unsigned int u) {
  return __uint_as_float(u & 0xffff0000u);
}

// ---------- f32 -> bf16 elementwise ----------
__global__ __launch_bounds__(256) void cvt_kernel(const float* __restrict__ in,
                                                  unsigned short* __restrict__ out,
                                                  int n) {
  int i = blockIdx.x * 256 + threadIdx.x;
  if (i < n) out[i] = f2b(in[i]);
}

// ---------- geometry ----------
__global__ __launch_bounds__(256) void geom_kernel(const int* __restrict__ src,
                                                   const int* __restrict__ dst,
                                                   const float* __restrict__ pos,
                                                   float4* __restrict__ geom) {
  int e = blockIdx.x * 256 + threadIdx.x;
  if (e >= N_EDGES) return;
  int s = src[e], d = dst[e];
  float dx = pos[s * 3 + 0] - pos[d * 3 + 0];
  float dy = pos[s * 3 + 1] - pos[d * 3 + 1];
  float dz = pos[s * 3 + 2] - pos[d * 3 + 2];
  float dist = sqrtf(dx * dx + dy * dy + dz * dz);
  float inv = 1.f / (dist + 1e-8f);
  geom[e] = make_float4(dx * inv, dy * inv, dz * inv, dist);
}

// ---------- CSR build ----------
__global__ __launch_bounds__(256) void hist_kernel(const int* __restrict__ dst,
                                                   int* __restrict__ deg) {
  int e = blockIdx.x * 256 + threadIdx.x;
  if (e < N_EDGES) atomicAdd(&deg[dst[e]], 1);
}

__global__ __launch_bounds__(1024) void scan_kernel(const int* __restrict__ deg,
                                                    int* __restrict__ off, int n) {
  __shared__ int wsum[16];
  __shared__ int ctot;
  int t = threadIdx.x, lane = t & 63, w = t >> 6;
  int carry = 0;
  for (int base = 0; base < n; base += 1024) {
    int i = base + t;
    int v = (i < n) ? deg[i] : 0;
    int x = v;
#pragma unroll
    for (int dd = 1; dd < 64; dd <<= 1) {
      int y = __shfl_up(x, dd);
      if (lane >= dd) x += y;
    }
    if (lane == 63) wsum[w] = x;
    __syncthreads();
    if (w == 0 && lane < 16) {
      int self = wsum[lane];
      int xs = self;
#pragma unroll
      for (int dd = 1; dd < 16; dd <<= 1) {
        int y = __shfl_up(xs, dd);
        if (lane >= dd) xs += y;
      }
      wsum[lane] = xs - self;
      if (lane == 15) ctot = xs;
    }
    __syncthreads();
    if (i < n) off[i] = carry + wsum[w] + (x - v);
    carry += ctot;
    __syncthreads();
  }
  if (t == 0) off[n] = carry;
}

__global__ __launch_bounds__(256) void fill_kernel(const int* __restrict__ dst,
                                                   const int* __restrict__ off,
                                                   int* __restrict__ cursor,
                                                   int* __restrict__ eid) {
  int e = blockIdx.x * 256 + threadIdx.x;
  if (e >= N_EDGES) return;
  int d = dst[e];
  int p = atomicAdd(&cursor[d], 1);
  eid[off[d] + p] = e;
}

// ---------- init: s = embed[z] (f32 + bf16), v_b = 0 ----------
__global__ __launch_bounds__(256) void init_kernel(const int* __restrict__ z,
                                                   const float* __restrict__ embed,
                                                   float* __restrict__ s,
                                                   unsigned short* __restrict__ sb,
                                                   unsigned short* __restrict__ vb) {
  int idx = blockIdx.x * 256 + threadIdx.x;
  if (idx < N_NODES * 384) vb[idx] = 0;
  if (idx < N_NODES * 128) {
    int node = idx >> 7, c = idx & 127;
    float val = embed[z[node] * 128 + c];
    s[idx] = val;
    sb[idx] = f2b(val);
  }
}

// ---------- bf16 MFMA GEMM: BM=128, BN=64, 4 waves ----------
#define KMAX 256
__global__ __launch_bounds__(256) void gemm_bf16(
    const unsigned short* __restrict__ A1, int lda1,
    const unsigned short* __restrict__ A2, int lda2, int kSplit,
    const unsigned short* __restrict__ B, int ldb,
    const float* __restrict__ bias,
    void* __restrict__ C, int ldc, int M, int K, int doRelu, int outBf16) {
  __shared__ unsigned int Bt32[64][KMAX / 2 + 4];
  int t = threadIdx.x;
  int lane = t & 63, w = t >> 6;
  int n0 = blockIdx.x * 64, m0 = blockIdx.y * 128;
  {
    int c4 = (t & 15) * 4;
    for (int k = (t >> 4) * 2; k < K; k += 32) {
      uint2 va = *(const uint2*)&B[(size_t)k * ldb + n0 + c4];
      uint2 vb = *(const uint2*)&B[(size_t)(k + 1) * ldb + n0 + c4];
      Bt32[c4 + 0][k >> 1] = (va.x & 0xffffu) | (vb.x << 16);
      Bt32[c4 + 1][k >> 1] = (va.x >> 16) | (vb.x & 0xffff0000u);
      Bt32[c4 + 2][k >> 1] = (va.y & 0xffffu) | (vb.y << 16);
      Bt32[c4 + 3][k >> 1] = (va.y >> 16) | (vb.y & 0xffff0000u);
    }
  }
  __syncthreads();

  int row = lane & 15;
  int kg = lane >> 4;

  f32x4 acc[2][4];
#pragma unroll
  for (int rf = 0; rf < 2; ++rf)
#pragma unroll
    for (int nf = 0; nf < 4; ++nf) acc[rf][nf] = (f32x4){0.f, 0.f, 0.f, 0.f};

  for (int ks = 0; ks < K; ks += 32) {
    int kk = ks + kg * 8;
    short8 af[2];
#pragma unroll
    for (int rf = 0; rf < 2; ++rf) {
      int mrow = m0 + w * 32 + rf * 16 + row;
      if (mrow >= M) mrow = M - 1;
      const unsigned short* Ap;
      int kloc;
      if (kk < kSplit) { Ap = A1 + (size_t)mrow * lda1; kloc = kk; }
      else             { Ap = A2 + (size_t)mrow * lda2; kloc = kk - kSplit; }
      af[rf] = *(const short8*)&Ap[kloc];
    }
#pragma unroll
    for (int nf = 0; nf < 4; ++nf) {
      short8 bf = *(const short8*)((const unsigned short*)Bt32[nf * 16 + row] + kk);
#pragma unroll
      for (int rf = 0; rf < 2; ++rf)
        acc[rf][nf] = __builtin_amdgcn_mfma_f32_16x16x32_bf16(af[rf], bf,
                                                              acc[rf][nf], 0, 0, 0);
    }
  }

#pragma unroll
  for (int rf = 0; rf < 2; ++rf)
#pragma unroll
    for (int nf = 0; nf < 4; ++nf)
#pragma unroll
      for (int r = 0; r < 4; ++r) {
        int gr = m0 + w * 32 + rf * 16 + kg * 4 + r;
        int gc = n0 + nf * 16 + row;
        if (gr < M) {
          float val = acc[rf][nf][r] + (bias ? bias[gc] : 0.f);
          if (doRelu) val = relu_f(val);
          if (outBf16) ((unsigned short*)C)[(size_t)gr * ldc + gc] = f2b(val);
          else         ((float*)C)[(size_t)gr * ldc + gc] = val;
        }
      }
}

// ---------- fused edge message: wave per node, bf16 everything ----------
// Lane owns channels {2*lane, 2*lane+1}. v-state is bf16-only.
__global__ __launch_bounds__(256) void msg_kernel(const int* __restrict__ off,
                                                  const int* __restrict__ eid_arr,
                                                  const int* __restrict__ src_arr,
                                                  const float4* __restrict__ geom,
                                                  const unsigned short* __restrict__ s_all_b,
                                                  const unsigned short* __restrict__ fwb,
                                                  const float* __restrict__ fb,
                                                  const float* __restrict__ s_in,
                                                  const unsigned short* __restrict__ v_in_b,
                                                  float* __restrict__ s_out,
                                                  unsigned short* __restrict__ s_out_b,
                                                  unsigned short* __restrict__ v_out_b) {
  int node = blockIdx.x * 4 + (threadIdx.x >> 6);
  if (node >= N_NODES) return;
  int lane = threadIdx.x & 63;
  int c2 = lane * 2;
  const float DELTA = 6.0f / 49.0f;
  const float INVD = 49.0f / 6.0f;
  const float CO = -0.5f * INVD * INVD;
  float fbr[3][2];
#pragma unroll
  for (int jj = 0; jj < 3; ++jj) {
    float2 f = *(const float2*)&fb[jj * 128 + c2];
    fbr[jj][0] = f.x; fbr[jj][1] = f.y;
  }
  float ds[2] = {0.f, 0.f};
  float dv[3][2] = {{0.f}};
  int e0 = off[node], e1 = off[node + 1];

  for (int q = e0; q < e1; ++q) {
    int e = eid_arr[q];
    int s = src_arr[e];
    float4 gm = geom[e];
    float d = gm.w;
    float wv[3][2];
#pragma unroll
    for (int jj = 0; jj < 3; ++jj) { wv[jj][0] = fbr[jj][0]; wv[jj][1] = fbr[jj][1]; }
    int glo = max(0, (int)ceilf(d * INVD - 8.f));
    int ghi = min(NGAUSS - 1, (int)floorf(d * INVD + 8.f));
    for (int g = glo; g <= ghi; ++g) {
      float diff = d - g * DELTA;
      float r = __expf(CO * diff * diff);
      const unsigned short* fr = fwb + (size_t)g * 384 + c2;
#pragma unroll
      for (int jj = 0; jj < 3; ++jj) {
        unsigned int f = *(const unsigned int*)&fr[jj * 128];
        wv[jj][0] = fmaf(r, b2f_lo(f), wv[jj][0]);
        wv[jj][1] = fmaf(r, b2f_hi(f), wv[jj][1]);
      }
    }
    const unsigned short* pas = s_all_b + (size_t)s * 384 + c2;
    const unsigned short* pav = v_in_b + (size_t)s * 384 + c2;
    unsigned int a_s[3] = {*(const unsigned int*)&pas[0],
                           *(const unsigned int*)&pas[128],
                           *(const unsigned int*)&pas[256]};
    unsigned int a_v[3] = {*(const unsigned int*)&pav[0],
                           *(const unsigned int*)&pav[128],
                           *(const unsigned int*)&pav[256]};
    float gt[3][2];
#pragma unroll
    for (int jj = 0; jj < 3; ++jj) {
      gt[jj][0] = b2f_lo(a_s[jj]) * wv[jj][0];
      gt[jj][1] = b2f_hi(a_s[jj]) * wv[jj][1];
    }
    ds[0] += gt[0][0];
    ds[1] += gt[0][1];
    float dn[3] = {gm.x, gm.y, gm.z};
#pragma unroll
    for (int dd = 0; dd < 3; ++dd) {
      dv[dd][0] = fmaf(b2f_lo(a_v[dd]), gt[1][0], fmaf(dn[dd], gt[2][0], dv[dd][0]));
      dv[dd][1] = fmaf(b2f_hi(a_v[dd]), gt[1][1], fmaf(dn[dd], gt[2][1], dv[dd][1]));
    }
  }

  size_t sb = (size_t)node * 128 + c2;
  float2 si = *(const float2*)&s_in[sb];
  float2 so = make_float2(si.x + ds[0], si.y + ds[1]);
  *(float2*)&s_out[sb] = so;
  *(unsigned int*)&s_out_b[sb] =
      (unsigned int)f2b(so.x) | ((unsigned int)f2b(so.y) << 16);
#pragma unroll
  for (int dd = 0; dd < 3; ++dd) {
    size_t vb = (size_t)node * 384 + dd * 128 + c2;
    unsigned int vi = *(const unsigned int*)&v_in_b[vb];
    float vo0 = b2f_lo(vi) + dv[dd][0];
    float vo1 = b2f_hi(vi) + dv[dd][1];
    *(unsigned int*)&v_out_b[vb] =
        (unsigned int)f2b(vo0) | ((unsigned int)f2b(vo1) << 16);
  }
}

// ---------- v_norm from bf16 V buffer [N*3,256] (V1 = cols 0..127) ----------
__global__ __launch_bounds__(256) void vnorm_kernel(const unsigned short* __restrict__ V12b,
                                                    unsigned short* __restrict__ vnb) {
  int idx = blockIdx.x * 256 + threadIdx.x;   // over N_NODES*32
  if (idx >= N_NODES * 32) return;
  int node = idx >> 5, c4 = (idx & 31) * 4;
  size_t b = (size_t)node * 768 + c4;
  ushort4 x = *(const ushort4*)&V12b[b];
  ushort4 y = *(const ushort4*)&V12b[b + 256];
  ushort4 zz = *(const ushort4*)&V12b[b + 512];
  ushort4 o;
  o.x = f2b(sqrtf(b2f(x.x) * b2f(x.x) + b2f(y.x) * b2f(y.x) + b2f(zz.x) * b2f(zz.x)));
  o.y = f2b(sqrtf(b2f(x.y) * b2f(x.y) + b2f(y.y) * b2f(y.y) + b2f(zz.y) * b2f(zz.y)));
  o.z = f2b(sqrtf(b2f(x.z) * b2f(x.z) + b2f(y.z) * b2f(y.z) + b2f(zz.z) * b2f(zz.z)));
  o.w = f2b(sqrtf(b2f(x.w) * b2f(x.w) + b2f(y.w) * b2f(y.w) + b2f(zz.w) * b2f(zz.w)));
  *(ushort4*)&vnb[(size_t)node * 128 + c4] = o;
}

// ---------- per-layer update: s += a ; v = v*b + V2*c (all-bf16 v path) ----------
__global__ __launch_bounds__(256) void update_kernel(const float* __restrict__ s_msg,
                                                     const unsigned short* __restrict__ v_msg_b,
                                                     const unsigned short* __restrict__ u_b,
                                                     const unsigned short* __restrict__ V12b,
                                                     float* __restrict__ s_out,
                                                     unsigned short* __restrict__ s_out_b,
                                                     unsigned short* __restrict__ v_out_b) {
  int idx = blockIdx.x * 256 + threadIdx.x;   // over N_NODES*32
  if (idx >= N_NODES * 32) return;
  int node = idx >> 5, c4 = (idx & 31) * 4;
  size_t ub = (size_t)node * 384 + c4;
  ushort4 a4 = *(const ushort4*)&u_b[ub];
  ushort4 b4 = *(const ushort4*)&u_b[ub + 128];
  ushort4 c4v = *(const ushort4*)&u_b[ub + 256];
  size_t sb = (size_t)node * 128 + c4;
  float4 sm = *(const float4*)&s_msg[sb];
  float4 so = make_float4(sm.x + b2f(a4.x), sm.y + b2f(a4.y),
                          sm.z + b2f(a4.z), sm.w + b2f(a4.w));
  *(float4*)&s_out[sb] = so;
  ushort4 sob = {f2b(so.x), f2b(so.y), f2b(so.z), f2b(so.w)};
  *(ushort4*)&s_out_b[sb] = sob;
  float bb[4] = {b2f(b4.x), b2f(b4.y), b2f(b4.z), b2f(b4.w)};
  float cc[4] = {b2f(c4v.x), b2f(c4v.y), b2f(c4v.z), b2f(c4v.w)};
#pragma unroll
  for (int dd = 0; dd < 3; ++dd) {
    size_t vb = (size_t)node * 384 + dd * 128 + c4;
    size_t vbv = (size_t)node * 768 + dd * 256 + 128 + c4;
    ushort4 vm = *(const ushort4*)&v_msg_b[vb];
    ushort4 v2 = *(const ushort4*)&V12b[vbv];
    ushort4 vo;
    vo.x = f2b(b2f(vm.x) * bb[0] + b2f(v2.x) * cc[0]);
    vo.y = f2b(b2f(vm.y) * bb[1] + b2f(v2.y) * cc[1]);
    vo.z = f2b(b2f(vm.z) * bb[2] + b2f(v2.z) * cc[2]);
    vo.w = f2b(b2f(vm.w) * bb[3] + b2f(v2.w) * cc[3]);
    *(ushort4*)&v_out_b[vb] = vo;
  }
}

// ---------- readout part 2: y = relu_h @ w2, pooled ----------
__global__ __launch_bounds__(256) void readout2_kernel(const float* __restrict__ ro_h,
                                                       const float* __restrict__ w2,
                                                       const int* __restrict__ batch,
                                                       float* __restrict__ pool,
                                                       float* __restrict__ cnt) {
  int node = blockIdx.x * 4 + (threadIdx.x >> 6);
  if (node >= N_NODES) return;
  int lane = threadIdx.x & 63;
  float y = ro_h[(size_t)node * 64 + lane] * w2[lane];
#pragma unroll
  for (int o = 32; o > 0; o >>= 1) y += __shfl_xor(y, o);
  if (lane == 0) {
    int b = batch[node];
    atomicAdd(&pool[b], y);
    atomicAdd(&cnt[b], 1.0f);
  }
}

__global__ void final_kernel(const float* __restrict__ pool,
                             const float* __restrict__ cnt,
                             const float* __restrict__ b2,
                             float* __restrict__ out) {
  int g = threadIdx.x;
  if (g < NGRAPH) out[g] = (pool[g] + cnt[g] * b2[0]) / fmaxf(cnt[g], 1.0f);
}

// ---------- host ----------
extern "C" void kernel_launch(void* const* d_in, const int* in_sizes, int n_in,
                              void* d_out, int out_size, void* d_ws, size_t ws_size,
                              hipStream_t stream) {
  const int*   z      = (const int*)d_in[0];
  const float* pos    = (const float*)d_in[1];
  const int*   esrc   = (const int*)d_in[2];
  const int*   edst   = esrc + N_EDGES;
  const int*   batch  = (const int*)d_in[3];
  const float* embed  = (const float*)d_in[4];
  const float* msg_w1 = (const float*)d_in[5];
  const float* msg_b1 = (const float*)d_in[6];
  const float* msg_w2 = (const float*)d_in[7];
  const float* msg_b2 = (const float*)d_in[8];
  const float* filt_w = (const float*)d_in[9];
  const float* filt_b = (const float*)d_in[10];
  const float* vec_w  = (const float*)d_in[11];
  const float* upd_w1 = (const float*)d_in[12];
  const float* upd_b1 = (const float*)d_in[13];
  const float* upd_w2 = (const float*)d_in[14];
  const float* upd_b2 = (const float*)d_in[15];
  const float* ro_w1  = (const float*)d_in[16];
  const float* ro_b1  = (const float*)d_in[17];
  const float* ro_w2  = (const float*)d_in[18];
  const float* ro_b2  = (const float*)d_in[19];
  (void)in_sizes; (void)n_in; (void)out_size;

  void* wsp = nullptr;
  if (hipGetSymbolAddress(&wsp, HIP_SYMBOL(g_ws)) != hipSuccess || wsp == nullptr) {
    wsp = d_ws;
  }
  char* wsb = (char*)wsp;
  size_t o = 0;
  auto alloc = [&](size_t bytes) -> void* {
    void* p = wsb + o;
    o += (bytes + 255) & ~(size_t)255;
    return p;
  };
  float4* geom   = (float4*)alloc(sizeof(float4) * N_EDGES);
  int* csr_off   = (int*)alloc(4ull * (N_NODES + 1));
  int* deg       = (int*)alloc(4ull * N_NODES);
  int* cursor    = (int*)alloc(4ull * N_NODES);
  int* csr_eid   = (int*)alloc(4ull * N_EDGES);
  float* sA      = (float*)alloc(4ull * N_NODES * 128);
  float* sB      = (float*)alloc(4ull * N_NODES * 128);
  float* ro_h    = (float*)alloc(4ull * N_NODES * 64);
  unsigned short* s_all_b = (unsigned short*)alloc(2ull * N_NODES * 384);
  unsigned short* sAb    = (unsigned short*)alloc(2ull * N_NODES * 128);
  unsigned short* sBb    = (unsigned short*)alloc(2ull * N_NODES * 128);
  unsigned short* vAb    = (unsigned short*)alloc(2ull * N_NODES * 384);
  unsigned short* vBb    = (unsigned short*)alloc(2ull * N_NODES * 384);
  unsigned short* vnb    = (unsigned short*)alloc(2ull * N_NODES * 128);
  unsigned short* hidden = (unsigned short*)alloc(2ull * N_NODES * 128);
  unsigned short* Vbuf_b = (unsigned short*)alloc(2ull * N_NODES * 768);  // V1|V2
  unsigned short* ubuf_b = (unsigned short*)alloc(2ull * N_NODES * 384);
  unsigned short* wb_m1  = (unsigned short*)alloc(2ull * NLAY * 128 * 128);
  unsigned short* wb_m2  = (unsigned short*)alloc(2ull * NLAY * 128 * 384);
  unsigned short* wb_vw  = (unsigned short*)alloc(2ull * NLAY * 128 * 256);
  unsigned short* wb_u1  = (unsigned short*)alloc(2ull * NLAY * 256 * 128);
  unsigned short* wb_u2  = (unsigned short*)alloc(2ull * NLAY * 128 * 384);
  unsigned short* wb_fw  = (unsigned short*)alloc(2ull * NLAY * 50 * 384);
  unsigned short* wb_ro  = (unsigned short*)alloc(2ull * 128 * 64);
  float* pool    = (float*)alloc(4ull * NGRAPH);
  float* cnt     = (float*)alloc(4ull * NGRAPH);

  if (wsb == (char*)d_ws && o > ws_size) return;

  hipMemsetAsync(deg, 0, 4ull * N_NODES, stream);
  hipMemsetAsync(cursor, 0, 4ull * N_NODES, stream);
  hipMemsetAsync(pool, 0, 4ull * NGRAPH, stream);
  hipMemsetAsync(cnt, 0, 4ull * NGRAPH, stream);

  auto cvt = [&](const float* in, unsigned short* out, int n) {
    cvt_kernel<<<(n + 255) / 256, 256, 0, stream>>>(in, out, n);
  };
  cvt(msg_w1, wb_m1, NLAY * 128 * 128);
  cvt(msg_w2, wb_m2, NLAY * 128 * 384);
  cvt(vec_w,  wb_vw, NLAY * 128 * 256);
  cvt(upd_w1, wb_u1, NLAY * 256 * 128);
  cvt(upd_w2, wb_u2, NLAY * 128 * 384);
  cvt(filt_w, wb_fw, NLAY * 50 * 384);
  cvt(ro_w1,  wb_ro, 128 * 64);

  geom_kernel<<<(N_EDGES + 255) / 256, 256, 0, stream>>>(esrc, edst, pos, geom);
  hist_kernel<<<(N_EDGES + 255) / 256, 256, 0, stream>>>(edst, deg);
  scan_kernel<<<1, 1024, 0, stream>>>(deg, csr_off, N_NODES);
  fill_kernel<<<(N_EDGES + 255) / 256, 256, 0, stream>>>(edst, csr_off, cursor, csr_eid);
  init_kernel<<<(N_NODES * 384 + 255) / 256, 256, 0, stream>>>(z, embed, sA, sAb, vAb);

  const int BIG = 1 << 30;
  const int GY40 = (N_NODES + 127) / 128;        // 313
  const int GY120 = (N_NODES * 3 + 127) / 128;   // 938
  for (int i = 0; i < NLAY; ++i) {
    const float* mb1 = msg_b1 + (size_t)i * 128;
    const float* mb2 = msg_b2 + (size_t)i * 384;
    const float* fbv = filt_b + (size_t)i * 384;
    const float* ub1 = upd_b1 + (size_t)i * 128;
    const float* ub2 = upd_b2 + (size_t)i * 384;
    const unsigned short* m1 = wb_m1 + (size_t)i * 128 * 128;
    const unsigned short* m2 = wb_m2 + (size_t)i * 128 * 384;
    const unsigned short* vw = wb_vw + (size_t)i * 128 * 256;
    const unsigned short* u1 = wb_u1 + (size_t)i * 256 * 128;
    const unsigned short* u2 = wb_u2 + (size_t)i * 128 * 384;
    const unsigned short* fwb = wb_fw + (size_t)i * 50 * 384;

    gemm_bf16<<<dim3(2, GY40), 256, 0, stream>>>(sAb, 128, sAb, 128, BIG, m1, 128, mb1,
                                                 hidden, 128, N_NODES, 128, 1, 1);
    gemm_bf16<<<dim3(6, GY40), 256, 0, stream>>>(hidden, 128, hidden, 128, BIG, m2, 384,
                                                 mb2, s_all_b, 384, N_NODES, 128, 0, 1);
    msg_kernel<<<N_NODES / 4, 256, 0, stream>>>(csr_off, csr_eid, esrc, geom,
                                                s_all_b, fwb, fbv, sA, vAb,
                                                sB, sBb, vBb);
    gemm_bf16<<<dim3(4, GY120), 256, 0, stream>>>(vBb, 128, vBb, 128, BIG, vw, 256,
                                                  nullptr, Vbuf_b, 256, N_NODES * 3,
                                                  128, 0, 1);
    vnorm_kernel<<<(N_NODES * 32 + 255) / 256, 256, 0, stream>>>(Vbuf_b, vnb);
    gemm_bf16<<<dim3(2, GY40), 256, 0, stream>>>(sBb, 128, vnb, 128, 128, u1, 128, ub1,
                                                 hidden, 128, N_NODES, 256, 1, 1);
    gemm_bf16<<<dim3(6, GY40), 256, 0, stream>>>(hidden, 128, hidden, 128, BIG, u2, 384,
                                                 ub2, ubuf_b, 384, N_NODES, 128, 0, 1);
    update_kernel<<<(N_NODES * 32 + 255) / 256, 256, 0, stream>>>(sB, vBb, ubuf_b,
                                                                  Vbuf_b, sA, sAb, vAb);
  }

  gemm_bf16<<<dim3(1, GY40), 256, 0, stream>>>(sAb, 128, sAb, 128, BIG, wb_ro, 64,
                                               ro_b1, ro_h, 64, N_NODES, 128, 1, 0);
  readout2_kernel<<<N_NODES / 4, 256, 0, stream>>>(ro_h, ro_w2, batch, pool, cnt);
  final_kernel<<<1, 256, 0, stream>>>(pool, cnt, ro_b2, (float*)d_out);
}